// Round 9
// baseline (2208.621 us; speedup 1.0000x reference)
//
#include <hip/hip_runtime.h>

#define NN 100000
#define NNP 100032        // gemm1 row padding (1563*64)
#define NZR (782 * 128)   // zbf rows = NBUC*128 = 100096
#define NE 1600000
#define NBUC 782          // buckets of 128 dst nodes
#define NBLKA 256         // binning blocks
#define CHA 6250          // edges per binning block
#define LG (NBUC * NBLKA) // 200192 = 391*512

typedef __attribute__((ext_vector_type(8))) short short8;   // 8 bf16
typedef __attribute__((ext_vector_type(4))) float f32x4;

// ---------------------------------------------------------------------------
__device__ __forceinline__ unsigned short f2bf(float f) {
    unsigned int u = __float_as_uint(f);
    u += 0x7FFFu + ((u >> 16) & 1u);
    return (unsigned short)(u >> 16);
}
__device__ __forceinline__ float ubf(unsigned short h) {
    return __uint_as_float((unsigned int)h << 16);
}
__device__ __forceinline__ float bf_lo(unsigned int u) { return __uint_as_float(u << 16); }
__device__ __forceinline__ float bf_hi(unsigned int u) { return __uint_as_float(u & 0xFFFF0000u); }

// split a float into bf16 hi + bf16 residual, packed into short8 lanes
__device__ __forceinline__ void split8(const float* v, short8& h8, short8& l8) {
    #pragma unroll
    for (int q = 0; q < 8; ++q) {
        unsigned short h = f2bf(v[q]);
        h8[q] = (short)h;
        l8[q] = (short)f2bf(v[q] - ubf(h));
    }
}

// ---------------------------------------------------------------------------
// weights: transpose + hi/lo split  (w1t[n][k], w2t[n][k])
__global__ void convw_kernel(const float* __restrict__ W1, const float* __restrict__ W2,
                             unsigned short* __restrict__ w1th, unsigned short* __restrict__ w1tl,
                             unsigned short* __restrict__ w2th, unsigned short* __restrict__ w2tl) {
    int n = blockIdx.x;       // 0..191
    int k = threadIdx.x;      // 0..127
    if (n < 128) {
        float w = W1[k * 128 + n];
        unsigned short h = f2bf(w);
        w1th[n * 128 + k] = h;
        w1tl[n * 128 + k] = f2bf(w - ubf(h));
    } else {
        int n2 = n - 128;
        float w = W2[k * 64 + n2];
        unsigned short h = f2bf(w);
        w2th[n2 * 128 + k] = h;
        w2tl[n2 * 128 + k] = f2bf(w - ubf(h));
    }
}

// ---------------------------------------------------------------------------
// Pass A: per-block bucket histogram -> G[bucket][block]
__global__ void binA_kernel(const int* __restrict__ dst, int* __restrict__ G, int E) {
    __shared__ int hist[NBUC];
    int t = threadIdx.x;
    for (int i = t; i < NBUC; i += 256) hist[i] = 0;
    __syncthreads();
    int s0 = blockIdx.x * CHA;
    int s1 = min(E, s0 + CHA);
    for (int i = s0 + t; i < s1; i += 256) atomicAdd(&hist[dst[i] >> 7], 1);
    __syncthreads();
    for (int i = t; i < NBUC; i += 256) G[i * NBLKA + blockIdx.x] = hist[i];
}

__global__ void gsum_kernel(const int* __restrict__ G, int* __restrict__ gb) {
    __shared__ int s[512];
    int t = threadIdx.x;
    s[t] = G[blockIdx.x * 512 + t];
    __syncthreads();
    for (int o = 256; o > 0; o >>= 1) {
        if (t < o) s[t] += s[t + o];
        __syncthreads();
    }
    if (t == 0) gb[blockIdx.x] = s[0];
}

__global__ void scanb_kernel(int* __restrict__ bsum, int nb) {
    __shared__ int s[512];
    int t = threadIdx.x;
    s[t] = (t < nb) ? bsum[t] : 0;
    __syncthreads();
    for (int o = 1; o < 512; o <<= 1) {
        int v = (t >= o) ? s[t - o] : 0;
        __syncthreads();
        if (t >= o) s[t] += v;
        __syncthreads();
    }
    if (t < nb) bsum[t] = (t == 0) ? 0 : s[t - 1];   // exclusive
}

__global__ void gscan_kernel(int* __restrict__ G, const int* __restrict__ gb) {
    __shared__ int s[512];
    int t = threadIdx.x;
    int i = blockIdx.x * 512 + t;
    int v = G[i];
    s[t] = v;
    __syncthreads();
    for (int o = 1; o < 512; o <<= 1) {
        int u = (t >= o) ? s[t - o] : 0;
        __syncthreads();
        if (t >= o) s[t] += u;
        __syncthreads();
    }
    G[i] = gb[blockIdx.x] + s[t] - v;   // exclusive
}

// Pass B: scatter packed (src<<7 | dst&127) into bucket-grouped ebuf
__global__ void binB_kernel(const int* __restrict__ src, const int* __restrict__ dst,
                            const int* __restrict__ G, unsigned int* __restrict__ ebuf,
                            int E) {
    __shared__ int cur[NBUC];
    int t = threadIdx.x;
    for (int i = t; i < NBUC; i += 256) cur[i] = G[i * NBLKA + blockIdx.x];
    __syncthreads();
    int s0 = blockIdx.x * CHA;
    int s1 = min(E, s0 + CHA);
    for (int i = s0 + t; i < s1; i += 256) {
        int d = dst[i];
        int b = d >> 7;
        int pos = atomicAdd(&cur[b], 1);
        ebuf[pos] = ((unsigned int)src[i] << 7) | (unsigned int)(d & 127);
    }
}

// ---------------------------------------------------------------------------
// GEMM1 fused with fp32->hi/lo conversion: ybf = bf16(x @ W1)
// 256 thr (4 waves), 64 rows/block, 3-term error-compensated MFMA
__global__ __launch_bounds__(256) void gemm1f_kernel(
    const float* __restrict__ x,
    const unsigned short* __restrict__ w1th, const unsigned short* __restrict__ w1tl,
    unsigned short* __restrict__ ybf) {
    const int wid = threadIdx.x >> 6;
    const int lane = threadIdx.x & 63;
    const int rbase = blockIdx.x * 64 + wid * 16;
    const int r = lane & 15;
    const int kg = lane >> 4;
    const int rc = min(rbase + r, NN - 1);   // clamp dead tail rows

    f32x4 acc[8];
    #pragma unroll
    for (int j = 0; j < 8; ++j) acc[j] = (f32x4){0.0f, 0.0f, 0.0f, 0.0f};

    #pragma unroll
    for (int kk = 0; kk < 4; ++kk) {
        const int ko = kk * 32 + kg * 8;
        float v[8];
        *reinterpret_cast<float4*>(&v[0]) = *reinterpret_cast<const float4*>(x + (size_t)rc * 128 + ko);
        *reinterpret_cast<float4*>(&v[4]) = *reinterpret_cast<const float4*>(x + (size_t)rc * 128 + ko + 4);
        short8 a_h, a_l;
        split8(v, a_h, a_l);
        #pragma unroll
        for (int j = 0; j < 8; ++j) {
            short8 b_h = *reinterpret_cast<const short8*>((const short*)w1th + (j * 16 + r) * 128 + ko);
            short8 b_l = *reinterpret_cast<const short8*>((const short*)w1tl + (j * 16 + r) * 128 + ko);
            acc[j] = __builtin_amdgcn_mfma_f32_16x16x32_bf16(a_h, b_h, acc[j], 0, 0, 0);
            acc[j] = __builtin_amdgcn_mfma_f32_16x16x32_bf16(a_h, b_l, acc[j], 0, 0, 0);
            acc[j] = __builtin_amdgcn_mfma_f32_16x16x32_bf16(a_l, b_h, acc[j], 0, 0, 0);
        }
    }

    // C/D: col = lane&15, row = kg*4 + q
    #pragma unroll
    for (int j = 0; j < 8; ++j) {
        #pragma unroll
        for (int q = 0; q < 4; ++q) {
            ybf[(size_t)(rbase + kg * 4 + q) * 128 + j * 16 + r] = f2bf(acc[j][q]);
        }
    }
}

// ---------------------------------------------------------------------------
// aggfuse1: per-bucket LDS aggregation of y + epilogue + fused GEMM2 -> zbf
// LDS acc layout swizzled: acc[node][feat ^ ((node&7)<<2)]
__global__ __launch_bounds__(512) void aggfuse1_kernel(
    const unsigned int* __restrict__ ebuf, const int* __restrict__ G,
    const unsigned short* __restrict__ ybf, const float* __restrict__ b1,
    const unsigned short* __restrict__ w2th, const unsigned short* __restrict__ w2tl,
    unsigned short* __restrict__ zbf, float* __restrict__ invg, int N) {
    __shared__ float acc[128][128];
    __shared__ int cnt[128];

    const int t = threadIdx.x;
    const int b = blockIdx.x;
    const int nodeBase = b << 7;
    const int segStart = G[b * NBLKA];
    const int segEnd = (b + 1 < NBUC) ? G[(b + 1) * NBLKA] : NE;

    // zero accumulators
    for (int i = t; i < 128 * 128 / 4; i += 512) {
        reinterpret_cast<float4*>(&acc[0][0])[i] = make_float4(0.f, 0.f, 0.f, 0.f);
    }
    if (t < 128) cnt[t] = 0;
    __syncthreads();

    // edge accumulation: full wave per edge, 2-edge unroll
    const int wv = t >> 6;
    const int lane = t & 63;
    const unsigned int* yb = (const unsigned int*)ybf;  // row = 64 uints
    int i = segStart + wv * 2;
    for (; i + 1 < segEnd; i += 16) {
        unsigned int e0 = (unsigned int)__builtin_amdgcn_readfirstlane((int)ebuf[i]);
        unsigned int e1 = (unsigned int)__builtin_amdgcn_readfirstlane((int)ebuf[i + 1]);
        int s0 = e0 >> 7, dl0 = e0 & 127;
        int s1 = e1 >> 7, dl1 = e1 & 127;
        unsigned int u0 = yb[(size_t)s0 * 64 + lane];
        unsigned int u1 = yb[(size_t)s1 * 64 + lane];
        int f0 = 2 * lane;
        int sw0 = (dl0 & 7) << 2, sw1 = (dl1 & 7) << 2;
        atomicAdd(&acc[dl0][f0 ^ sw0], bf_lo(u0));
        atomicAdd(&acc[dl0][(f0 + 1) ^ sw0], bf_hi(u0));
        atomicAdd(&acc[dl1][f0 ^ sw1], bf_lo(u1));
        atomicAdd(&acc[dl1][(f0 + 1) ^ sw1], bf_hi(u1));
        if (lane == 0) atomicAdd(&cnt[dl0], 1);
        else if (lane == 1) atomicAdd(&cnt[dl1], 1);
    }
    if (i < segEnd) {
        unsigned int e0 = (unsigned int)__builtin_amdgcn_readfirstlane((int)ebuf[i]);
        int s0 = e0 >> 7, dl0 = e0 & 127;
        unsigned int u0 = yb[(size_t)s0 * 64 + lane];
        int f0 = 2 * lane;
        int sw0 = (dl0 & 7) << 2;
        atomicAdd(&acc[dl0][f0 ^ sw0], bf_lo(u0));
        atomicAdd(&acc[dl0][(f0 + 1) ^ sw0], bf_hi(u0));
        if (lane == 0) atomicAdd(&cnt[dl0], 1);
    }
    __syncthreads();

    // epilogue: h1 = relu((acc + y_self) * inv + b1), stored back into acc (fp32)
    {
        const int node = t >> 2;          // 4 threads per node
        const int part = t & 3;           // 32 feats each
        const int n = nodeBase + node;
        const float ivn = 1.0f / (float)(cnt[node] + 1);
        if (part == 0 && n < N) invg[n] = ivn;
        if (n < N) {
            const unsigned int* yrow = yb + (size_t)n * 64 + part * 16;
            const int sw = (node & 7) << 2;
            #pragma unroll 4
            for (int q = 0; q < 16; ++q) {
                unsigned int u = yrow[q];
                int fp = part * 32 + 2 * q;
                int i0 = fp ^ sw;
                float v0 = fmaxf(fmaf(acc[node][i0] + bf_lo(u), ivn, b1[fp]), 0.0f);
                float v1 = fmaxf(fmaf(acc[node][i0 + 1] + bf_hi(u), ivn, b1[fp + 1]), 0.0f);
                acc[node][i0] = v0;
                acc[node][i0 + 1] = v1;
            }
        }
    }
    __syncthreads();

    // fused GEMM2: zbf[bucket rows] = bf16(h1 @ W2), 8 waves x 16 rows
    const int r = lane & 15;
    const int kg = lane >> 4;
    const int lrow = wv * 16 + r;
    const int sw = (lrow & 7) << 2;

    f32x4 acc2[4];
    #pragma unroll
    for (int j = 0; j < 4; ++j) acc2[j] = (f32x4){0.0f, 0.0f, 0.0f, 0.0f};

    #pragma unroll
    for (int kk = 0; kk < 4; ++kk) {
        const int ko = kk * 32 + kg * 8;
        float v[8];
        *reinterpret_cast<float4*>(&v[0]) = *reinterpret_cast<const float4*>(&acc[lrow][ko ^ sw]);
        *reinterpret_cast<float4*>(&v[4]) = *reinterpret_cast<const float4*>(&acc[lrow][(ko + 4) ^ sw]);
        short8 a_h, a_l;
        split8(v, a_h, a_l);
        #pragma unroll
        for (int j = 0; j < 4; ++j) {
            short8 b_h = *reinterpret_cast<const short8*>((const short*)w2th + (j * 16 + r) * 128 + ko);
            short8 b_l = *reinterpret_cast<const short8*>((const short*)w2tl + (j * 16 + r) * 128 + ko);
            acc2[j] = __builtin_amdgcn_mfma_f32_16x16x32_bf16(a_h, b_h, acc2[j], 0, 0, 0);
            acc2[j] = __builtin_amdgcn_mfma_f32_16x16x32_bf16(a_h, b_l, acc2[j], 0, 0, 0);
            acc2[j] = __builtin_amdgcn_mfma_f32_16x16x32_bf16(a_l, b_h, acc2[j], 0, 0, 0);
        }
    }

    #pragma unroll
    for (int j = 0; j < 4; ++j) {
        #pragma unroll
        for (int q = 0; q < 4; ++q) {
            zbf[(size_t)(nodeBase + wv * 16 + kg * 4 + q) * 64 + j * 16 + r] = f2bf(acc2[j][q]);
        }
    }
}

// ---------------------------------------------------------------------------
// aggB2: per-bucket LDS aggregation of z + epilogue -> out
__global__ __launch_bounds__(512) void aggB2_kernel(
    const unsigned int* __restrict__ ebuf, const int* __restrict__ G,
    const unsigned short* __restrict__ zbf, const float* __restrict__ invg,
    const float* __restrict__ b2, float* __restrict__ out, int N) {
    __shared__ float acc[128][64];

    const int t = threadIdx.x;
    const int b = blockIdx.x;
    const int nodeBase = b << 7;
    const int segStart = G[b * NBLKA];
    const int segEnd = (b + 1 < NBUC) ? G[(b + 1) * NBLKA] : NE;

    for (int i = t; i < 128 * 64 / 4; i += 512) {
        reinterpret_cast<float4*>(&acc[0][0])[i] = make_float4(0.f, 0.f, 0.f, 0.f);
    }
    __syncthreads();

    // half-wave per edge (32 lanes x 4B = 128B row)
    const int wv = t >> 6;
    const int lane = t & 63;
    const int half = lane >> 5;
    const int l32 = lane & 31;
    const unsigned int* zb = (const unsigned int*)zbf;   // row = 32 uints
    for (int i = segStart + wv * 2 + half; i < segEnd; i += 16) {
        unsigned int e = ebuf[i];
        int s0 = e >> 7, dl = e & 127;
        unsigned int u = zb[(size_t)s0 * 32 + l32];
        atomicAdd(&acc[dl][2 * l32], bf_lo(u));
        atomicAdd(&acc[dl][2 * l32 + 1], bf_hi(u));
    }
    __syncthreads();

    // epilogue: out = (acc + z_self) * inv + b2
    const int node = t >> 2;
    const int part = t & 3;          // 16 feats each
    const int n = nodeBase + node;
    if (n < N) {
        const float ivn = invg[n];
        const unsigned int* zrow = zb + (size_t)n * 32 + part * 8;
        float2* op = reinterpret_cast<float2*>(out + (size_t)n * 64 + part * 16);
        #pragma unroll
        for (int q = 0; q < 8; ++q) {
            unsigned int u = zrow[q];
            int fp = part * 16 + 2 * q;
            float2 rv;
            rv.x = fmaf(acc[node][fp] + bf_lo(u), ivn, b2[fp]);
            rv.y = fmaf(acc[node][fp + 1] + bf_hi(u), ivn, b2[fp + 1]);
            op[q] = rv;
        }
    }
}

// ---------------------------------------------------------------------------
extern "C" void kernel_launch(void* const* d_in, const int* in_sizes, int n_in,
                              void* d_out, int out_size, void* d_ws, size_t ws_size,
                              hipStream_t stream) {
    const float* x   = (const float*)d_in[0];
    const float* W1  = (const float*)d_in[1];
    const float* b1  = (const float*)d_in[2];
    const float* W2  = (const float*)d_in[3];
    const float* b2  = (const float*)d_in[4];
    const int* esrc  = (const int*)d_in[5];
    const int* edst  = (const int*)d_in[6];
    float* out = (float*)d_out;

    // workspace (~46 MB)
    char* p = (char*)d_ws;
    unsigned short* ybf = (unsigned short*)p;  p += (size_t)NNP * 128 * 2;   // 25.6 MB
    unsigned short* zbf = (unsigned short*)p;  p += (size_t)NZR * 64 * 2;    // 12.8 MB
    unsigned int* ebuf = (unsigned int*)p;     p += (size_t)NE * 4;          // 6.4 MB
    int* G = (int*)p;                          p += (size_t)LG * 4;          // 0.8 MB
    int* gb = (int*)p;                         p += 512 * 4;
    float* invg = (float*)p;                   p += (size_t)NN * 4;          // 0.4 MB
    unsigned short* w1th = (unsigned short*)p; p += 128 * 128 * 2;
    unsigned short* w1tl = (unsigned short*)p; p += 128 * 128 * 2;
    unsigned short* w2th = (unsigned short*)p; p += 64 * 128 * 2;
    unsigned short* w2tl = (unsigned short*)p; p += 64 * 128 * 2;

    // weights prep
    convw_kernel<<<192, 128, 0, stream>>>(W1, W2, w1th, w1tl, w2th, w2tl);

    // bucket-sort edges by dst bucket (no global atomics)
    binA_kernel<<<NBLKA, 256, 0, stream>>>(edst, G, NE);
    gsum_kernel<<<LG / 512, 512, 0, stream>>>(G, gb);
    scanb_kernel<<<1, 512, 0, stream>>>(gb, LG / 512);
    gscan_kernel<<<LG / 512, 512, 0, stream>>>(G, gb);
    binB_kernel<<<NBLKA, 256, 0, stream>>>(esrc, edst, G, ebuf, NE);

    // layer 1 GEMM (x fp32 -> hi/lo in-register, MFMA) -> ybf
    gemm1f_kernel<<<NNP / 64, 256, 0, stream>>>(x, w1th, w1tl, ybf);

    // fused: aggregate y per bucket + epilogue + GEMM2 -> zbf (+ invg)
    aggfuse1_kernel<<<NBUC, 512, 0, stream>>>(ebuf, G, ybf, b1, w2th, w2tl, zbf, invg, NN);

    // fused: aggregate z per bucket + epilogue -> out
    aggB2_kernel<<<NBUC, 512, 0, stream>>>(ebuf, G, zbf, invg, b2, out, NN);
}

// Round 10
// 388.046 us; speedup vs baseline: 5.6917x; 5.6917x over previous
//
#include <hip/hip_runtime.h>

#define NN 100000
#define NNP 100032        // padded rows for 64-row MFMA tiles (1563*64)
#define NE 1600000
#define NBUC 782          // buckets of 128 dst nodes
#define NBLKA 256         // binning blocks
#define CHA 6250          // edges per binning block
#define LG (NBUC * NBLKA) // 200192 = 391*512

typedef __attribute__((ext_vector_type(8))) short short8;   // 8 bf16
typedef __attribute__((ext_vector_type(4))) float f32x4;

// ---------------------------------------------------------------------------
__device__ __forceinline__ unsigned short f2bf(float f) {
    unsigned int u = __float_as_uint(f);
    u += 0x7FFFu + ((u >> 16) & 1u);
    return (unsigned short)(u >> 16);
}
__device__ __forceinline__ float ubf(unsigned short h) {
    return __uint_as_float((unsigned int)h << 16);
}
__device__ __forceinline__ float bf_lo(unsigned int u) { return __uint_as_float(u << 16); }
__device__ __forceinline__ float bf_hi(unsigned int u) { return __uint_as_float(u & 0xFFFF0000u); }

__device__ __forceinline__ void split8(const float* v, short8& h8, short8& l8) {
    #pragma unroll
    for (int q = 0; q < 8; ++q) {
        unsigned short h = f2bf(v[q]);
        h8[q] = (short)h;
        l8[q] = (short)f2bf(v[q] - ubf(h));
    }
}

// ---------------------------------------------------------------------------
// weights: transpose + hi/lo split  (w1t[n][k], w2t[n][k])
__global__ void convw_kernel(const float* __restrict__ W1, const float* __restrict__ W2,
                             unsigned short* __restrict__ w1th, unsigned short* __restrict__ w1tl,
                             unsigned short* __restrict__ w2th, unsigned short* __restrict__ w2tl) {
    int n = blockIdx.x;       // 0..191
    int k = threadIdx.x;      // 0..127
    if (n < 128) {
        float w = W1[k * 128 + n];
        unsigned short h = f2bf(w);
        w1th[n * 128 + k] = h;
        w1tl[n * 128 + k] = f2bf(w - ubf(h));
    } else {
        int n2 = n - 128;
        float w = W2[k * 64 + n2];
        unsigned short h = f2bf(w);
        w2th[n2 * 128 + k] = h;
        w2tl[n2 * 128 + k] = f2bf(w - ubf(h));
    }
}

// ---------------------------------------------------------------------------
// CSR build via LDS-binned bucket sort (proven in rounds 7-8)
__global__ void binA_kernel(const int* __restrict__ dst, int* __restrict__ G, int E) {
    __shared__ int hist[NBUC];
    int t = threadIdx.x;
    for (int i = t; i < NBUC; i += 256) hist[i] = 0;
    __syncthreads();
    int s0 = blockIdx.x * CHA;
    int s1 = min(E, s0 + CHA);
    for (int i = s0 + t; i < s1; i += 256) atomicAdd(&hist[dst[i] >> 7], 1);
    __syncthreads();
    for (int i = t; i < NBUC; i += 256) G[i * NBLKA + blockIdx.x] = hist[i];
}

__global__ void gsum_kernel(const int* __restrict__ G, int* __restrict__ gb) {
    __shared__ int s[512];
    int t = threadIdx.x;
    s[t] = G[blockIdx.x * 512 + t];
    __syncthreads();
    for (int o = 256; o > 0; o >>= 1) {
        if (t < o) s[t] += s[t + o];
        __syncthreads();
    }
    if (t == 0) gb[blockIdx.x] = s[0];
}

__global__ void scanb_kernel(int* __restrict__ bsum, int nb) {
    __shared__ int s[512];
    int t = threadIdx.x;
    s[t] = (t < nb) ? bsum[t] : 0;
    __syncthreads();
    for (int o = 1; o < 512; o <<= 1) {
        int v = (t >= o) ? s[t - o] : 0;
        __syncthreads();
        if (t >= o) s[t] += v;
        __syncthreads();
    }
    if (t < nb) bsum[t] = (t == 0) ? 0 : s[t - 1];   // exclusive
}

__global__ void gscan_kernel(int* __restrict__ G, const int* __restrict__ gb) {
    __shared__ int s[512];
    int t = threadIdx.x;
    int i = blockIdx.x * 512 + t;
    int v = G[i];
    s[t] = v;
    __syncthreads();
    for (int o = 1; o < 512; o <<= 1) {
        int u = (t >= o) ? s[t - o] : 0;
        __syncthreads();
        if (t >= o) s[t] += u;
        __syncthreads();
    }
    G[i] = gb[blockIdx.x] + s[t] - v;   // exclusive
}

// Pass B: 4B packed (src<<7 | dst&127) into bucket-grouped ebuf
__global__ void binB_kernel(const int* __restrict__ src, const int* __restrict__ dst,
                            const int* __restrict__ G, unsigned int* __restrict__ ebuf,
                            int E) {
    __shared__ int cur[NBUC];
    int t = threadIdx.x;
    for (int i = t; i < NBUC; i += 256) cur[i] = G[i * NBLKA + blockIdx.x];
    __syncthreads();
    int s0 = blockIdx.x * CHA;
    int s1 = min(E, s0 + CHA);
    for (int i = s0 + t; i < s1; i += 256) {
        int d = dst[i];
        int b = d >> 7;
        int pos = atomicAdd(&cur[b], 1);
        ebuf[pos] = ((unsigned int)src[i] << 7) | (unsigned int)(d & 127);
    }
}

// Pass C: per-bucket node-level fill -> rowptr, invg, col (node-sorted src)
__global__ void fillC_kernel(const unsigned int* __restrict__ ebuf,
                             const int* __restrict__ G, int* __restrict__ rowptr,
                             float* __restrict__ invg, int* __restrict__ col, int E, int N) {
    __shared__ int cnt[128];
    __shared__ int sc[128];
    int b = blockIdx.x;
    int t = threadIdx.x;
    int segStart = G[b * NBLKA];
    int segEnd = (b + 1 < NBUC) ? G[(b + 1) * NBLKA] : E;
    int nodeBase = b << 7;

    if (t < 128) cnt[t] = 0;
    __syncthreads();
    for (int i = segStart + t; i < segEnd; i += 256) {
        atomicAdd(&cnt[ebuf[i] & 127], 1);
    }
    __syncthreads();
    if (t < 128) sc[t] = cnt[t];
    __syncthreads();
    for (int o = 1; o < 128; o <<= 1) {
        int v = 0;
        if (t < 128 && t >= o) v = sc[t - o];
        __syncthreads();
        if (t < 128 && t >= o) sc[t] += v;
        __syncthreads();
    }
    if (t < 128) {
        int excl = (t == 0) ? 0 : sc[t - 1];
        int n = nodeBase + t;
        if (n < N) {
            rowptr[n] = segStart + excl;
            invg[n] = 1.0f / (float)(cnt[t] + 1);
        }
        sc[t] = segStart + excl;   // cursor
    }
    if (b == 0 && t == 0) rowptr[N] = E;
    __syncthreads();
    for (int i = segStart + t; i < segEnd; i += 256) {
        unsigned int e = ebuf[i];
        int pos = atomicAdd(&sc[e & 127], 1);
        col[pos] = (int)(e >> 7);
    }
}

// ---------------------------------------------------------------------------
// GEMM1 (fused fp32->hi/lo): ybf = bf16(x @ W1); 3-term compensated MFMA
__global__ __launch_bounds__(256) void gemm1f_kernel(
    const float* __restrict__ x,
    const unsigned short* __restrict__ w1th, const unsigned short* __restrict__ w1tl,
    unsigned short* __restrict__ ybf) {
    const int wid = threadIdx.x >> 6;
    const int lane = threadIdx.x & 63;
    const int rbase = blockIdx.x * 64 + wid * 16;
    const int r = lane & 15;
    const int kg = lane >> 4;
    const int rc = min(rbase + r, NN - 1);   // clamp tail rows (pad rows get row NN-1)

    f32x4 acc[8];
    #pragma unroll
    for (int j = 0; j < 8; ++j) acc[j] = (f32x4){0.0f, 0.0f, 0.0f, 0.0f};

    #pragma unroll
    for (int kk = 0; kk < 4; ++kk) {
        const int ko = kk * 32 + kg * 8;
        float v[8];
        *reinterpret_cast<float4*>(&v[0]) = *reinterpret_cast<const float4*>(x + (size_t)rc * 128 + ko);
        *reinterpret_cast<float4*>(&v[4]) = *reinterpret_cast<const float4*>(x + (size_t)rc * 128 + ko + 4);
        short8 a_h, a_l;
        split8(v, a_h, a_l);
        #pragma unroll
        for (int j = 0; j < 8; ++j) {
            short8 b_h = *reinterpret_cast<const short8*>((const short*)w1th + (j * 16 + r) * 128 + ko);
            short8 b_l = *reinterpret_cast<const short8*>((const short*)w1tl + (j * 16 + r) * 128 + ko);
            acc[j] = __builtin_amdgcn_mfma_f32_16x16x32_bf16(a_h, b_h, acc[j], 0, 0, 0);
            acc[j] = __builtin_amdgcn_mfma_f32_16x16x32_bf16(a_h, b_l, acc[j], 0, 0, 0);
            acc[j] = __builtin_amdgcn_mfma_f32_16x16x32_bf16(a_l, b_h, acc[j], 0, 0, 0);
        }
    }

    // C/D: col = lane&15, row = kg*4 + q  [m89-verified]
    #pragma unroll
    for (int j = 0; j < 8; ++j) {
        #pragma unroll
        for (int q = 0; q < 4; ++q) {
            ybf[(size_t)(rbase + kg * 4 + q) * 128 + j * 16 + r] = f2bf(acc[j][q]);
        }
    }
}

// GEMM2: zbf = bf16(h1 @ W2); A rows clamped (pad rows never consumed)
__global__ __launch_bounds__(256) void gemm2m_kernel(
    const unsigned short* __restrict__ h1h, const unsigned short* __restrict__ h1l,
    const unsigned short* __restrict__ w2th, const unsigned short* __restrict__ w2tl,
    unsigned short* __restrict__ zbf) {
    const int wid = threadIdx.x >> 6;
    const int lane = threadIdx.x & 63;
    const int rbase = blockIdx.x * 64 + wid * 16;
    const int r = lane & 15;
    const int kg = lane >> 4;
    const int rc = min(rbase + r, NN - 1);

    f32x4 acc[4];
    #pragma unroll
    for (int j = 0; j < 4; ++j) acc[j] = (f32x4){0.0f, 0.0f, 0.0f, 0.0f};

    const short* hhp = (const short*)h1h;
    const short* hlp = (const short*)h1l;

    #pragma unroll
    for (int kk = 0; kk < 4; ++kk) {
        const int ko = kk * 32 + kg * 8;
        short8 a_h = *reinterpret_cast<const short8*>(hhp + (size_t)rc * 128 + ko);
        short8 a_l = *reinterpret_cast<const short8*>(hlp + (size_t)rc * 128 + ko);
        #pragma unroll
        for (int j = 0; j < 4; ++j) {
            short8 b_h = *reinterpret_cast<const short8*>((const short*)w2th + (j * 16 + r) * 128 + ko);
            short8 b_l = *reinterpret_cast<const short8*>((const short*)w2tl + (j * 16 + r) * 128 + ko);
            acc[j] = __builtin_amdgcn_mfma_f32_16x16x32_bf16(a_h, b_h, acc[j], 0, 0, 0);
            acc[j] = __builtin_amdgcn_mfma_f32_16x16x32_bf16(a_h, b_l, acc[j], 0, 0, 0);
            acc[j] = __builtin_amdgcn_mfma_f32_16x16x32_bf16(a_l, b_h, acc[j], 0, 0, 0);
        }
    }

    #pragma unroll
    for (int j = 0; j < 4; ++j) {
        #pragma unroll
        for (int q = 0; q < 4; ++q) {
            zbf[(size_t)(rbase + kg * 4 + q) * 64 + j * 16 + r] = f2bf(acc[j][q]);
        }
    }
}

// ---------------------------------------------------------------------------
// agg1: h1 = relu((sum_src y[src] + y[n]) * inv + b1) -> bf16 hi/lo
// wave/node, lane owns feats {2l,2l+1}, 8 gathers in flight
__global__ void agg1_kernel(const unsigned short* __restrict__ ybf,
                            const int* __restrict__ rowptr, const int* __restrict__ col,
                            const float* __restrict__ invg, const float* __restrict__ b1,
                            unsigned short* __restrict__ h1h, unsigned short* __restrict__ h1l,
                            int N) {
    int wave = (blockIdx.x * blockDim.x + threadIdx.x) >> 6;
    if (wave >= N) return;
    int lane = threadIdx.x & 63;
    int start = rowptr[wave], end = rowptr[wave + 1];
    const unsigned int* yb = (const unsigned int*)ybf;   // row stride 64 uints

    float ax0 = 0, ay0 = 0, ax1 = 0, ay1 = 0, ax2 = 0, ay2 = 0, ax3 = 0, ay3 = 0;
    float ax4 = 0, ay4 = 0, ax5 = 0, ay5 = 0, ax6 = 0, ay6 = 0, ax7 = 0, ay7 = 0;
    int e = start;
    for (; e + 7 < end; e += 8) {
        int s0 = __builtin_amdgcn_readfirstlane(col[e]);
        int s1 = __builtin_amdgcn_readfirstlane(col[e + 1]);
        int s2 = __builtin_amdgcn_readfirstlane(col[e + 2]);
        int s3 = __builtin_amdgcn_readfirstlane(col[e + 3]);
        int s4 = __builtin_amdgcn_readfirstlane(col[e + 4]);
        int s5 = __builtin_amdgcn_readfirstlane(col[e + 5]);
        int s6 = __builtin_amdgcn_readfirstlane(col[e + 6]);
        int s7 = __builtin_amdgcn_readfirstlane(col[e + 7]);
        unsigned int u0 = yb[(size_t)s0 * 64 + lane];
        unsigned int u1 = yb[(size_t)s1 * 64 + lane];
        unsigned int u2 = yb[(size_t)s2 * 64 + lane];
        unsigned int u3 = yb[(size_t)s3 * 64 + lane];
        unsigned int u4 = yb[(size_t)s4 * 64 + lane];
        unsigned int u5 = yb[(size_t)s5 * 64 + lane];
        unsigned int u6 = yb[(size_t)s6 * 64 + lane];
        unsigned int u7 = yb[(size_t)s7 * 64 + lane];
        ax0 += bf_lo(u0); ay0 += bf_hi(u0);
        ax1 += bf_lo(u1); ay1 += bf_hi(u1);
        ax2 += bf_lo(u2); ay2 += bf_hi(u2);
        ax3 += bf_lo(u3); ay3 += bf_hi(u3);
        ax4 += bf_lo(u4); ay4 += bf_hi(u4);
        ax5 += bf_lo(u5); ay5 += bf_hi(u5);
        ax6 += bf_lo(u6); ay6 += bf_hi(u6);
        ax7 += bf_lo(u7); ay7 += bf_hi(u7);
    }
    for (; e + 3 < end; e += 4) {
        int s0 = __builtin_amdgcn_readfirstlane(col[e]);
        int s1 = __builtin_amdgcn_readfirstlane(col[e + 1]);
        int s2 = __builtin_amdgcn_readfirstlane(col[e + 2]);
        int s3 = __builtin_amdgcn_readfirstlane(col[e + 3]);
        unsigned int u0 = yb[(size_t)s0 * 64 + lane];
        unsigned int u1 = yb[(size_t)s1 * 64 + lane];
        unsigned int u2 = yb[(size_t)s2 * 64 + lane];
        unsigned int u3 = yb[(size_t)s3 * 64 + lane];
        ax0 += bf_lo(u0); ay0 += bf_hi(u0);
        ax1 += bf_lo(u1); ay1 += bf_hi(u1);
        ax2 += bf_lo(u2); ay2 += bf_hi(u2);
        ax3 += bf_lo(u3); ay3 += bf_hi(u3);
    }
    for (; e < end; ++e) {
        int s0 = __builtin_amdgcn_readfirstlane(col[e]);
        unsigned int u0 = yb[(size_t)s0 * 64 + lane];
        ax0 += bf_lo(u0); ay0 += bf_hi(u0);
    }
    float sx = ((ax0 + ax1) + (ax2 + ax3)) + ((ax4 + ax5) + (ax6 + ax7));
    float sy = ((ay0 + ay1) + (ay2 + ay3)) + ((ay4 + ay5) + (ay6 + ay7));

    unsigned int us = yb[(size_t)wave * 64 + lane];
    float2 bb = *reinterpret_cast<const float2*>(b1 + lane * 2);
    float iv = invg[wave];
    float rx = fmaxf(fmaf(sx + bf_lo(us), iv, bb.x), 0.0f);
    float ry = fmaxf(fmaf(sy + bf_hi(us), iv, bb.y), 0.0f);

    ushort2 h, l;
    h.x = f2bf(rx); l.x = f2bf(rx - ubf(h.x));
    h.y = f2bf(ry); l.y = f2bf(ry - ubf(h.y));
    *reinterpret_cast<ushort2*>(h1h + (size_t)wave * 128 + lane * 2) = h;
    *reinterpret_cast<ushort2*>(h1l + (size_t)wave * 128 + lane * 2) = l;
}

// agg2: out = (sum_src z[src] + z[n]) * inv + b2
// wave/node: two half-waves interleave the SAME edge list (no divergence),
// each lane 4B; combine across halves with shfl_xor(32)
__global__ void agg2_kernel(const unsigned short* __restrict__ zbf,
                            const int* __restrict__ rowptr, const int* __restrict__ col,
                            const float* __restrict__ invg, const float* __restrict__ b2,
                            float* __restrict__ out, int N) {
    int node = (blockIdx.x * blockDim.x + threadIdx.x) >> 6;
    if (node >= N) return;
    int lane = threadIdx.x & 63;
    int half = lane >> 5;
    int l32 = lane & 31;
    int start = rowptr[node], end = rowptr[node + 1];
    const unsigned int* zb = (const unsigned int*)zbf;   // row stride 32 uints

    float ax0 = 0, ay0 = 0, ax1 = 0, ay1 = 0, ax2 = 0, ay2 = 0, ax3 = 0, ay3 = 0;
    int i = start + half;
    for (; i + 6 < end; i += 8) {
        int s0 = col[i], s1 = col[i + 2], s2 = col[i + 4], s3 = col[i + 6];
        unsigned int u0 = zb[(size_t)s0 * 32 + l32];
        unsigned int u1 = zb[(size_t)s1 * 32 + l32];
        unsigned int u2 = zb[(size_t)s2 * 32 + l32];
        unsigned int u3 = zb[(size_t)s3 * 32 + l32];
        ax0 += bf_lo(u0); ay0 += bf_hi(u0);
        ax1 += bf_lo(u1); ay1 += bf_hi(u1);
        ax2 += bf_lo(u2); ay2 += bf_hi(u2);
        ax3 += bf_lo(u3); ay3 += bf_hi(u3);
    }
    for (; i < end; i += 2) {
        unsigned int u0 = zb[(size_t)col[i] * 32 + l32];
        ax0 += bf_lo(u0); ay0 += bf_hi(u0);
    }
    float sx = (ax0 + ax1) + (ax2 + ax3);
    float sy = (ay0 + ay1) + (ay2 + ay3);
    sx += __shfl_xor(sx, 32);
    sy += __shfl_xor(sy, 32);

    if (half == 0) {
        unsigned int us = zb[(size_t)node * 32 + l32];
        float2 bb = *reinterpret_cast<const float2*>(b2 + l32 * 2);
        float iv = invg[node];
        float2 r;
        r.x = fmaf(sx + bf_lo(us), iv, bb.x);
        r.y = fmaf(sy + bf_hi(us), iv, bb.y);
        *reinterpret_cast<float2*>(out + (size_t)node * 64 + l32 * 2) = r;
    }
}

// ---------------------------------------------------------------------------
extern "C" void kernel_launch(void* const* d_in, const int* in_sizes, int n_in,
                              void* d_out, int out_size, void* d_ws, size_t ws_size,
                              hipStream_t stream) {
    const float* x   = (const float*)d_in[0];
    const float* W1  = (const float*)d_in[1];
    const float* b1  = (const float*)d_in[2];
    const float* W2  = (const float*)d_in[3];
    const float* b2  = (const float*)d_in[4];
    const int* esrc  = (const int*)d_in[5];
    const int* edst  = (const int*)d_in[6];
    float* out = (float*)d_out;

    // workspace (~104 MB, within proven budget)
    char* p = (char*)d_ws;
    unsigned short* ybf = (unsigned short*)p;  p += (size_t)NNP * 128 * 2;   // 25.6 MB
    unsigned short* h1h = (unsigned short*)p;  p += (size_t)NNP * 128 * 2;   // 25.6 MB
    unsigned short* h1l = (unsigned short*)p;  p += (size_t)NNP * 128 * 2;   // 25.6 MB
    unsigned short* zbf = (unsigned short*)p;  p += (size_t)NNP * 64 * 2;    // 12.8 MB
    unsigned int* ebuf = (unsigned int*)p;     p += (size_t)NE * 4;          // 6.4 MB
    int* col = (int*)p;                        p += (size_t)NE * 4;          // 6.4 MB
    int* G = (int*)p;                          p += (size_t)LG * 4;          // 0.8 MB
    int* gb = (int*)p;                         p += 512 * 4;
    int* rowptr = (int*)p;                     p += (size_t)(NN + 4) * 4;
    float* invg = (float*)p;                   p += (size_t)NN * 4;
    unsigned short* w1th = (unsigned short*)p; p += 128 * 128 * 2;
    unsigned short* w1tl = (unsigned short*)p; p += 128 * 128 * 2;
    unsigned short* w2th = (unsigned short*)p; p += 64 * 128 * 2;
    unsigned short* w2tl = (unsigned short*)p; p += 64 * 128 * 2;

    // weights prep
    convw_kernel<<<192, 128, 0, stream>>>(W1, W2, w1th, w1tl, w2th, w2tl);

    // CSR build (bucket sort, no global atomics)
    binA_kernel<<<NBLKA, 256, 0, stream>>>(edst, G, NE);
    gsum_kernel<<<LG / 512, 512, 0, stream>>>(G, gb);
    scanb_kernel<<<1, 512, 0, stream>>>(gb, LG / 512);
    gscan_kernel<<<LG / 512, 512, 0, stream>>>(G, gb);
    binB_kernel<<<NBLKA, 256, 0, stream>>>(esrc, edst, G, ebuf, NE);
    fillC_kernel<<<NBUC, 256, 0, stream>>>(ebuf, G, rowptr, invg, col, NE, NN);

    // layer 1: ybf = bf16(x@W1) (fused conversion); h1 hi/lo via gather-agg
    gemm1f_kernel<<<NNP / 64, 256, 0, stream>>>(x, w1th, w1tl, ybf);
    agg1_kernel<<<NN / 4, 256, 0, stream>>>(ybf, rowptr, col, invg, b1, h1h, h1l, NN);

    // layer 2: zbf = bf16(h1@W2); out via gather-agg
    gemm2m_kernel<<<NNP / 64, 256, 0, stream>>>(h1h, h1l, w2th, w2tl, zbf);
    agg2_kernel<<<NN / 4, 256, 0, stream>>>(zbf, rowptr, col, invg, b2, out, NN);
}

// Round 12
// 356.270 us; speedup vs baseline: 6.1993x; 1.0892x over previous
//
#include <hip/hip_runtime.h>

#define NN 100000
#define NNP 100096        // 782*128 rows (128-row GEMM blocks)
#define NE 1600000
#define NBUC 782          // buckets of 128 dst nodes
#define NBLKA 256         // binning blocks
#define CHA 6250          // edges per binning block
#define LG (NBUC * NBLKA) // 200192 = 391*512

typedef __attribute__((ext_vector_type(8))) short short8;   // 8 bf16
typedef __attribute__((ext_vector_type(4))) float f32x4;

// ---------------------------------------------------------------------------
__device__ __forceinline__ unsigned short f2bf(float f) {
    unsigned int u = __float_as_uint(f);
    u += 0x7FFFu + ((u >> 16) & 1u);
    return (unsigned short)(u >> 16);
}
__device__ __forceinline__ float ubf(unsigned short h) {
    return __uint_as_float((unsigned int)h << 16);
}
__device__ __forceinline__ float bf_lo(unsigned int u) { return __uint_as_float(u << 16); }
__device__ __forceinline__ float bf_hi(unsigned int u) { return __uint_as_float(u & 0xFFFF0000u); }

__device__ __forceinline__ void split8(const float* v, short8& h8, short8& l8) {
    #pragma unroll
    for (int q = 0; q < 8; ++q) {
        unsigned short h = f2bf(v[q]);
        h8[q] = (short)h;
        l8[q] = (short)f2bf(v[q] - ubf(h));
    }
}

// ---------------------------------------------------------------------------
// weights: transpose + hi/lo split  (w1t[n][k], w2t[n][k])
__global__ void convw_kernel(const float* __restrict__ W1, const float* __restrict__ W2,
                             unsigned short* __restrict__ w1th, unsigned short* __restrict__ w1tl,
                             unsigned short* __restrict__ w2th, unsigned short* __restrict__ w2tl) {
    int n = blockIdx.x;       // 0..191
    int k = threadIdx.x;      // 0..127
    if (n < 128) {
        float w = W1[k * 128 + n];
        unsigned short h = f2bf(w);
        w1th[n * 128 + k] = h;
        w1tl[n * 128 + k] = f2bf(w - ubf(h));
    } else {
        int n2 = n - 128;
        float w = W2[k * 64 + n2];
        unsigned short h = f2bf(w);
        w2th[n2 * 128 + k] = h;
        w2tl[n2 * 128 + k] = f2bf(w - ubf(h));
    }
}

// ---------------------------------------------------------------------------
// CSR build via LDS-binned bucket sort (proven rounds 7-10)
__global__ void binA_kernel(const int* __restrict__ dst, int* __restrict__ G, int E) {
    __shared__ int hist[NBUC];
    int t = threadIdx.x;
    for (int i = t; i < NBUC; i += 256) hist[i] = 0;
    __syncthreads();
    int s0 = blockIdx.x * CHA;
    int s1 = min(E, s0 + CHA);
    for (int i = s0 + t; i < s1; i += 256) atomicAdd(&hist[dst[i] >> 7], 1);
    __syncthreads();
    for (int i = t; i < NBUC; i += 256) G[i * NBLKA + blockIdx.x] = hist[i];
}

__global__ void gsum_kernel(const int* __restrict__ G, int* __restrict__ gb) {
    __shared__ int s[512];
    int t = threadIdx.x;
    s[t] = G[blockIdx.x * 512 + t];
    __syncthreads();
    for (int o = 256; o > 0; o >>= 1) {
        if (t < o) s[t] += s[t + o];
        __syncthreads();
    }
    if (t == 0) gb[blockIdx.x] = s[0];
}

__global__ void scanb_kernel(int* __restrict__ bsum, int nb) {
    __shared__ int s[512];
    int t = threadIdx.x;
    s[t] = (t < nb) ? bsum[t] : 0;
    __syncthreads();
    for (int o = 1; o < 512; o <<= 1) {
        int v = (t >= o) ? s[t - o] : 0;
        __syncthreads();
        if (t >= o) s[t] += v;
        __syncthreads();
    }
    if (t < nb) bsum[t] = (t == 0) ? 0 : s[t - 1];   // exclusive
}

__global__ void gscan_kernel(int* __restrict__ G, const int* __restrict__ gb) {
    __shared__ int s[512];
    int t = threadIdx.x;
    int i = blockIdx.x * 512 + t;
    int v = G[i];
    s[t] = v;
    __syncthreads();
    for (int o = 1; o < 512; o <<= 1) {
        int u = (t >= o) ? s[t - o] : 0;
        __syncthreads();
        if (t >= o) s[t] += u;
        __syncthreads();
    }
    G[i] = gb[blockIdx.x] + s[t] - v;   // exclusive
}

__global__ void binB_kernel(const int* __restrict__ src, const int* __restrict__ dst,
                            const int* __restrict__ G, unsigned int* __restrict__ ebuf,
                            int E) {
    __shared__ int cur[NBUC];
    int t = threadIdx.x;
    for (int i = t; i < NBUC; i += 256) cur[i] = G[i * NBLKA + blockIdx.x];
    __syncthreads();
    int s0 = blockIdx.x * CHA;
    int s1 = min(E, s0 + CHA);
    for (int i = s0 + t; i < s1; i += 256) {
        int d = dst[i];
        int b = d >> 7;
        int pos = atomicAdd(&cur[b], 1);
        ebuf[pos] = ((unsigned int)src[i] << 7) | (unsigned int)(d & 127);
    }
}

__global__ void fillC_kernel(const unsigned int* __restrict__ ebuf,
                             const int* __restrict__ G, int* __restrict__ rowptr,
                             float* __restrict__ invg, int* __restrict__ col, int E, int N) {
    __shared__ int cnt[128];
    __shared__ int sc[128];
    int b = blockIdx.x;
    int t = threadIdx.x;
    int segStart = G[b * NBLKA];
    int segEnd = (b + 1 < NBUC) ? G[(b + 1) * NBLKA] : E;
    int nodeBase = b << 7;

    if (t < 128) cnt[t] = 0;
    __syncthreads();
    for (int i = segStart + t; i < segEnd; i += 256) {
        atomicAdd(&cnt[ebuf[i] & 127], 1);
    }
    __syncthreads();
    if (t < 128) sc[t] = cnt[t];
    __syncthreads();
    for (int o = 1; o < 128; o <<= 1) {
        int v = 0;
        if (t < 128 && t >= o) v = sc[t - o];
        __syncthreads();
        if (t < 128 && t >= o) sc[t] += v;
        __syncthreads();
    }
    if (t < 128) {
        int excl = (t == 0) ? 0 : sc[t - 1];
        int n = nodeBase + t;
        if (n < N) {
            rowptr[n] = segStart + excl;
            invg[n] = 1.0f / (float)(cnt[t] + 1);
        }
        sc[t] = segStart + excl;   // cursor
    }
    if (b == 0 && t == 0) rowptr[N] = E;
    __syncthreads();
    for (int i = segStart + t; i < segEnd; i += 256) {
        unsigned int e = ebuf[i];
        int pos = atomicAdd(&sc[e & 127], 1);
        col[pos] = (int)(e >> 7);
    }
}

// ---------------------------------------------------------------------------
// GEMM1 (fused fp32->hi/lo): ybf = bf16(x @ W1); 3-term compensated MFMA.
// M=2 register blocking: 256 thr (4 waves), 128 rows/block, wave = 32 rows.
// B fragments loaded once per (kk,j) and reused for both row tiles.
__global__ __launch_bounds__(256) void gemm1f_kernel(
    const float* __restrict__ x,
    const unsigned short* __restrict__ w1th, const unsigned short* __restrict__ w1tl,
    unsigned short* __restrict__ ybf) {
    const int wid = threadIdx.x >> 6;
    const int lane = threadIdx.x & 63;
    const int r = lane & 15;
    const int kg = lane >> 4;
    const int rbase = blockIdx.x * 128 + wid * 32;
    const int rc0 = min(rbase + r, NN - 1);        // clamp tail rows
    const int rc1 = min(rbase + 16 + r, NN - 1);

    f32x4 acc[2][8];
    #pragma unroll
    for (int m = 0; m < 2; ++m)
        #pragma unroll
        for (int j = 0; j < 8; ++j) acc[m][j] = (f32x4){0.f, 0.f, 0.f, 0.f};

    #pragma unroll
    for (int kk = 0; kk < 4; ++kk) {
        const int ko = kk * 32 + kg * 8;
        // A fragments for both row tiles (fused fp32->hi/lo split)
        float v0[8], v1[8];
        *reinterpret_cast<float4*>(&v0[0]) = *reinterpret_cast<const float4*>(x + (size_t)rc0 * 128 + ko);
        *reinterpret_cast<float4*>(&v0[4]) = *reinterpret_cast<const float4*>(x + (size_t)rc0 * 128 + ko + 4);
        *reinterpret_cast<float4*>(&v1[0]) = *reinterpret_cast<const float4*>(x + (size_t)rc1 * 128 + ko);
        *reinterpret_cast<float4*>(&v1[4]) = *reinterpret_cast<const float4*>(x + (size_t)rc1 * 128 + ko + 4);
        short8 a0h, a0l, a1h, a1l;
        split8(v0, a0h, a0l);
        split8(v1, a1h, a1l);
        #pragma unroll
        for (int j = 0; j < 8; ++j) {
            short8 b_h = *reinterpret_cast<const short8*>((const short*)w1th + (j * 16 + r) * 128 + ko);
            short8 b_l = *reinterpret_cast<const short8*>((const short*)w1tl + (j * 16 + r) * 128 + ko);
            acc[0][j] = __builtin_amdgcn_mfma_f32_16x16x32_bf16(a0h, b_h, acc[0][j], 0, 0, 0);
            acc[0][j] = __builtin_amdgcn_mfma_f32_16x16x32_bf16(a0h, b_l, acc[0][j], 0, 0, 0);
            acc[0][j] = __builtin_amdgcn_mfma_f32_16x16x32_bf16(a0l, b_h, acc[0][j], 0, 0, 0);
            acc[1][j] = __builtin_amdgcn_mfma_f32_16x16x32_bf16(a1h, b_h, acc[1][j], 0, 0, 0);
            acc[1][j] = __builtin_amdgcn_mfma_f32_16x16x32_bf16(a1h, b_l, acc[1][j], 0, 0, 0);
            acc[1][j] = __builtin_amdgcn_mfma_f32_16x16x32_bf16(a1l, b_h, acc[1][j], 0, 0, 0);
        }
    }

    // C/D: col = lane&15, row = kg*4 + q  [m89-verified]
    #pragma unroll
    for (int m = 0; m < 2; ++m) {
        #pragma unroll
        for (int j = 0; j < 8; ++j) {
            #pragma unroll
            for (int q = 0; q < 4; ++q) {
                ybf[(size_t)(rbase + m * 16 + kg * 4 + q) * 128 + j * 16 + r] = f2bf(acc[m][j][q]);
            }
        }
    }
}

// GEMM2: zbf = bf16(h1 @ W2); M=2 register blocking, direct global B loads.
__global__ __launch_bounds__(256) void gemm2m_kernel(
    const unsigned short* __restrict__ h1h, const unsigned short* __restrict__ h1l,
    const unsigned short* __restrict__ w2th, const unsigned short* __restrict__ w2tl,
    unsigned short* __restrict__ zbf) {
    const int wid = threadIdx.x >> 6;
    const int lane = threadIdx.x & 63;
    const int r = lane & 15;
    const int kg = lane >> 4;
    const int rbase = blockIdx.x * 128 + wid * 32;
    const int rc0 = min(rbase + r, NN - 1);
    const int rc1 = min(rbase + 16 + r, NN - 1);

    f32x4 acc[2][4];
    #pragma unroll
    for (int m = 0; m < 2; ++m)
        #pragma unroll
        for (int j = 0; j < 4; ++j) acc[m][j] = (f32x4){0.f, 0.f, 0.f, 0.f};

    const short* hhp = (const short*)h1h;
    const short* hlp = (const short*)h1l;

    #pragma unroll
    for (int kk = 0; kk < 4; ++kk) {
        const int ko = kk * 32 + kg * 8;
        short8 a0h = *reinterpret_cast<const short8*>(hhp + (size_t)rc0 * 128 + ko);
        short8 a0l = *reinterpret_cast<const short8*>(hlp + (size_t)rc0 * 128 + ko);
        short8 a1h = *reinterpret_cast<const short8*>(hhp + (size_t)rc1 * 128 + ko);
        short8 a1l = *reinterpret_cast<const short8*>(hlp + (size_t)rc1 * 128 + ko);
        #pragma unroll
        for (int j = 0; j < 4; ++j) {
            short8 b_h = *reinterpret_cast<const short8*>((const short*)w2th + (j * 16 + r) * 128 + ko);
            short8 b_l = *reinterpret_cast<const short8*>((const short*)w2tl + (j * 16 + r) * 128 + ko);
            acc[0][j] = __builtin_amdgcn_mfma_f32_16x16x32_bf16(a0h, b_h, acc[0][j], 0, 0, 0);
            acc[0][j] = __builtin_amdgcn_mfma_f32_16x16x32_bf16(a0h, b_l, acc[0][j], 0, 0, 0);
            acc[0][j] = __builtin_amdgcn_mfma_f32_16x16x32_bf16(a0l, b_h, acc[0][j], 0, 0, 0);
            acc[1][j] = __builtin_amdgcn_mfma_f32_16x16x32_bf16(a1h, b_h, acc[1][j], 0, 0, 0);
            acc[1][j] = __builtin_amdgcn_mfma_f32_16x16x32_bf16(a1h, b_l, acc[1][j], 0, 0, 0);
            acc[1][j] = __builtin_amdgcn_mfma_f32_16x16x32_bf16(a1l, b_h, acc[1][j], 0, 0, 0);
        }
    }

    #pragma unroll
    for (int m = 0; m < 2; ++m) {
        #pragma unroll
        for (int j = 0; j < 4; ++j) {
            #pragma unroll
            for (int q = 0; q < 4; ++q) {
                zbf[(size_t)(rbase + m * 16 + kg * 4 + q) * 64 + j * 16 + r] = f2bf(acc[m][j][q]);
            }
        }
    }
}

// ---------------------------------------------------------------------------
// agg1: h1 = relu((sum_src y[src] + y[n]) * inv + b1) -> bf16 hi/lo
__global__ void agg1_kernel(const unsigned short* __restrict__ ybf,
                            const int* __restrict__ rowptr, const int* __restrict__ col,
                            const float* __restrict__ invg, const float* __restrict__ b1,
                            unsigned short* __restrict__ h1h, unsigned short* __restrict__ h1l,
                            int N) {
    int wave = (blockIdx.x * blockDim.x + threadIdx.x) >> 6;
    if (wave >= N) return;
    int lane = threadIdx.x & 63;
    int start = rowptr[wave], end = rowptr[wave + 1];
    const unsigned int* yb = (const unsigned int*)ybf;   // row stride 64 uints

    float ax0 = 0, ay0 = 0, ax1 = 0, ay1 = 0, ax2 = 0, ay2 = 0, ax3 = 0, ay3 = 0;
    float ax4 = 0, ay4 = 0, ax5 = 0, ay5 = 0, ax6 = 0, ay6 = 0, ax7 = 0, ay7 = 0;
    int e = start;
    for (; e + 7 < end; e += 8) {
        int s0 = __builtin_amdgcn_readfirstlane(col[e]);
        int s1 = __builtin_amdgcn_readfirstlane(col[e + 1]);
        int s2 = __builtin_amdgcn_readfirstlane(col[e + 2]);
        int s3 = __builtin_amdgcn_readfirstlane(col[e + 3]);
        int s4 = __builtin_amdgcn_readfirstlane(col[e + 4]);
        int s5 = __builtin_amdgcn_readfirstlane(col[e + 5]);
        int s6 = __builtin_amdgcn_readfirstlane(col[e + 6]);
        int s7 = __builtin_amdgcn_readfirstlane(col[e + 7]);
        unsigned int u0 = yb[(size_t)s0 * 64 + lane];
        unsigned int u1 = yb[(size_t)s1 * 64 + lane];
        unsigned int u2 = yb[(size_t)s2 * 64 + lane];
        unsigned int u3 = yb[(size_t)s3 * 64 + lane];
        unsigned int u4 = yb[(size_t)s4 * 64 + lane];
        unsigned int u5 = yb[(size_t)s5 * 64 + lane];
        unsigned int u6 = yb[(size_t)s6 * 64 + lane];
        unsigned int u7 = yb[(size_t)s7 * 64 + lane];
        ax0 += bf_lo(u0); ay0 += bf_hi(u0);
        ax1 += bf_lo(u1); ay1 += bf_hi(u1);
        ax2 += bf_lo(u2); ay2 += bf_hi(u2);
        ax3 += bf_lo(u3); ay3 += bf_hi(u3);
        ax4 += bf_lo(u4); ay4 += bf_hi(u4);
        ax5 += bf_lo(u5); ay5 += bf_hi(u5);
        ax6 += bf_lo(u6); ay6 += bf_hi(u6);
        ax7 += bf_lo(u7); ay7 += bf_hi(u7);
    }
    for (; e + 3 < end; e += 4) {
        int s0 = __builtin_amdgcn_readfirstlane(col[e]);
        int s1 = __builtin_amdgcn_readfirstlane(col[e + 1]);
        int s2 = __builtin_amdgcn_readfirstlane(col[e + 2]);
        int s3 = __builtin_amdgcn_readfirstlane(col[e + 3]);
        unsigned int u0 = yb[(size_t)s0 * 64 + lane];
        unsigned int u1 = yb[(size_t)s1 * 64 + lane];
        unsigned int u2 = yb[(size_t)s2 * 64 + lane];
        unsigned int u3 = yb[(size_t)s3 * 64 + lane];
        ax0 += bf_lo(u0); ay0 += bf_hi(u0);
        ax1 += bf_lo(u1); ay1 += bf_hi(u1);
        ax2 += bf_lo(u2); ay2 += bf_hi(u2);
        ax3 += bf_lo(u3); ay3 += bf_hi(u3);
    }
    for (; e < end; ++e) {
        int s0 = __builtin_amdgcn_readfirstlane(col[e]);
        unsigned int u0 = yb[(size_t)s0 * 64 + lane];
        ax0 += bf_lo(u0); ay0 += bf_hi(u0);
    }
    float sx = ((ax0 + ax1) + (ax2 + ax3)) + ((ax4 + ax5) + (ax6 + ax7));
    float sy = ((ay0 + ay1) + (ay2 + ay3)) + ((ay4 + ay5) + (ay6 + ay7));

    unsigned int us = yb[(size_t)wave * 64 + lane];
    float2 bb = *reinterpret_cast<const float2*>(b1 + lane * 2);
    float iv = invg[wave];
    float rx = fmaxf(fmaf(sx + bf_lo(us), iv, bb.x), 0.0f);
    float ry = fmaxf(fmaf(sy + bf_hi(us), iv, bb.y), 0.0f);

    ushort2 h, l;
    h.x = f2bf(rx); l.x = f2bf(rx - ubf(h.x));
    h.y = f2bf(ry); l.y = f2bf(ry - ubf(h.y));
    *reinterpret_cast<ushort2*>(h1h + (size_t)wave * 128 + lane * 2) = h;
    *reinterpret_cast<ushort2*>(h1l + (size_t)wave * 128 + lane * 2) = l;
}

// agg2: out = (sum_src z[src] + z[n]) * inv + b2; wave/node, halves share list
__global__ void agg2_kernel(const unsigned short* __restrict__ zbf,
                            const int* __restrict__ rowptr, const int* __restrict__ col,
                            const float* __restrict__ invg, const float* __restrict__ b2,
                            float* __restrict__ out, int N) {
    int node = (blockIdx.x * blockDim.x + threadIdx.x) >> 6;
    if (node >= N) return;
    int lane = threadIdx.x & 63;
    int half = lane >> 5;
    int l32 = lane & 31;
    int start = rowptr[node], end = rowptr[node + 1];
    const unsigned int* zb = (const unsigned int*)zbf;   // row stride 32 uints

    float ax0 = 0, ay0 = 0, ax1 = 0, ay1 = 0, ax2 = 0, ay2 = 0, ax3 = 0, ay3 = 0;
    int i = start + half;
    for (; i + 6 < end; i += 8) {
        int s0 = col[i], s1 = col[i + 2], s2 = col[i + 4], s3 = col[i + 6];
        unsigned int u0 = zb[(size_t)s0 * 32 + l32];
        unsigned int u1 = zb[(size_t)s1 * 32 + l32];
        unsigned int u2 = zb[(size_t)s2 * 32 + l32];
        unsigned int u3 = zb[(size_t)s3 * 32 + l32];
        ax0 += bf_lo(u0); ay0 += bf_hi(u0);
        ax1 += bf_lo(u1); ay1 += bf_hi(u1);
        ax2 += bf_lo(u2); ay2 += bf_hi(u2);
        ax3 += bf_lo(u3); ay3 += bf_hi(u3);
    }
    for (; i < end; i += 2) {
        unsigned int u0 = zb[(size_t)col[i] * 32 + l32];
        ax0 += bf_lo(u0); ay0 += bf_hi(u0);
    }
    float sx = (ax0 + ax1) + (ax2 + ax3);
    float sy = (ay0 + ay1) + (ay2 + ay3);
    sx += __shfl_xor(sx, 32);
    sy += __shfl_xor(sy, 32);

    if (half == 0) {
        unsigned int us = zb[(size_t)node * 32 + l32];
        float2 bb = *reinterpret_cast<const float2*>(b2 + l32 * 2);
        float iv = invg[node];
        float2 r;
        r.x = fmaf(sx + bf_lo(us), iv, bb.x);
        r.y = fmaf(sy + bf_hi(us), iv, bb.y);
        *reinterpret_cast<float2*>(out + (size_t)node * 64 + l32 * 2) = r;
    }
}

// ---------------------------------------------------------------------------
extern "C" void kernel_launch(void* const* d_in, const int* in_sizes, int n_in,
                              void* d_out, int out_size, void* d_ws, size_t ws_size,
                              hipStream_t stream) {
    const float* x   = (const float*)d_in[0];
    const float* W1  = (const float*)d_in[1];
    const float* b1  = (const float*)d_in[2];
    const float* W2  = (const float*)d_in[3];
    const float* b2  = (const float*)d_in[4];
    const int* esrc  = (const int*)d_in[5];
    const int* edst  = (const int*)d_in[6];
    float* out = (float*)d_out;

    // workspace (~104 MB)
    char* p = (char*)d_ws;
    unsigned short* ybf = (unsigned short*)p;  p += (size_t)NNP * 128 * 2;   // 25.6 MB
    unsigned short* h1h = (unsigned short*)p;  p += (size_t)NNP * 128 * 2;   // 25.6 MB
    unsigned short* h1l = (unsigned short*)p;  p += (size_t)NNP * 128 * 2;   // 25.6 MB
    unsigned short* zbf = (unsigned short*)p;  p += (size_t)NNP * 64 * 2;    // 12.8 MB
    unsigned int* ebuf = (unsigned int*)p;     p += (size_t)NE * 4;          // 6.4 MB
    int* col = (int*)p;                        p += (size_t)NE * 4;          // 6.4 MB
    int* G = (int*)p;                          p += (size_t)LG * 4;          // 0.8 MB
    int* gb = (int*)p;                         p += 512 * 4;
    int* rowptr = (int*)p;                     p += (size_t)(NN + 4) * 4;
    float* invg = (float*)p;                   p += (size_t)NN * 4;
    unsigned short* w1th = (unsigned short*)p; p += 128 * 128 * 2;
    unsigned short* w1tl = (unsigned short*)p; p += 128 * 128 * 2;
    unsigned short* w2th = (unsigned short*)p; p += 64 * 128 * 2;
    unsigned short* w2tl = (unsigned short*)p; p += 64 * 128 * 2;

    // weights prep
    convw_kernel<<<192, 128, 0, stream>>>(W1, W2, w1th, w1tl, w2th, w2tl);

    // CSR build (bucket sort, no global atomics)
    binA_kernel<<<NBLKA, 256, 0, stream>>>(edst, G, NE);
    gsum_kernel<<<LG / 512, 512, 0, stream>>>(G, gb);
    scanb_kernel<<<1, 512, 0, stream>>>(gb, LG / 512);
    gscan_kernel<<<LG / 512, 512, 0, stream>>>(G, gb);
    binB_kernel<<<NBLKA, 256, 0, stream>>>(esrc, edst, G, ebuf, NE);
    fillC_kernel<<<NBUC, 256, 0, stream>>>(ebuf, G, rowptr, invg, col, NE, NN);

    // layer 1
    gemm1f_kernel<<<NNP / 128, 256, 0, stream>>>(x, w1th, w1tl, ybf);
    agg1_kernel<<<NN / 4, 256, 0, stream>>>(ybf, rowptr, col, invg, b1, h1h, h1l, NN);

    // layer 2
    gemm2m_kernel<<<NNP / 128, 256, 0, stream>>>(h1h, h1l, w2th, w2tl, zbf);
    agg2_kernel<<<NN / 4, 256, 0, stream>>>(zbf, rowptr, col, invg, b2, out, NN);
}